// Round 5
// baseline (626.937 us; speedup 1.0000x reference)
//
#include <hip/hip_runtime.h>
#include <cstddef>

// ---------------------------------------------------------------------------
// SimpleModuleNet. B=256, D=64, E=16, H=W=64, PROJ=512, FC=1024, NA=2.
//
// R2: 64->64 convs on matrix pipe (mfma_f32_16x16x32_f16, f16 hi/lo split,
//     lo plane scaled 2048 -> ~2^-22 error). NHWC activations.
// R3: fc1 on matrix pipe (in-kernel hi/lo staging, 40-f16 LDS stride,
//     reg prefetch, XCD-bijective swizzle, split-K 32).
// R4: proj rewritten as per-sample MFMA GEMM with in-lane 2x2 pool and
//     LDS-transposed COALESCED writes (was 8.6x write-amplified: 288MB vs
//     33.5MB ideal -> 100us). conv1 writes also LDS-transposed (same bug).
// ---------------------------------------------------------------------------

typedef _Float16 half8 __attribute__((ext_vector_type(8)));
typedef _Float16 half4_t __attribute__((ext_vector_type(4)));
typedef float f32x4 __attribute__((ext_vector_type(4)));

#define LO_SCALE 2048.0f
#define LO_INV (1.0f / 2048.0f)

// ---------------- generic weight transpose  [o][i](KxK) -> [(i*K+k)][o]
__global__ void transw_k(const float* __restrict__ src, float* __restrict__ dst,
                         int O, int I, int K, int total) {
    int id = blockIdx.x * 256 + threadIdx.x;
    if (id >= total) return;
    int OIK = O * I * K;
    int n = id / OIK, rem = id % OIK;
    int o = rem / (I * K), r2 = rem % (I * K);
    int i = r2 / K, k = r2 % K;
    dst[(size_t)n * OIK + (i * K + k) * O + o] = src[id];
}

// ---------------- conv weight transform: [layer][oc=64][ic=64][3][3] fp32 ->
// f16 fragment layout: idx = (((tap*2+icc)*4+nt)*64 + lane)*8 + j
__global__ void wxform_k(const float* __restrict__ src, _Float16* __restrict__ dst,
                         int nlayers) {
    int id = blockIdx.x * 256 + threadIdx.x;
    if (id >= nlayers * 36864) return;
    int layer = id / 36864, idx = id % 36864;
    int j = idx & 7, l = (idx >> 3) & 63, nt = (idx >> 9) & 3;
    int icc = (idx >> 11) & 1, tap = idx >> 12;
    int kl = (l >> 4) * 8 + j, ic = icc * 32 + kl, oc = nt * 16 + (l & 15);
    float v = src[(size_t)layer * 36864 + (oc * 64 + ic) * 9 + tap];
    _Float16 hi = (_Float16)v;
    _Float16 lo = (_Float16)((v - (float)hi) * LO_SCALE);
    dst[(size_t)layer * 73728 + idx] = hi;
    dst[(size_t)layer * 73728 + 36864 + idx] = lo;
}

// ---------------- proj weight transform: [512 oc][64 ic] fp32 -> B-frag hi/lo
// idx = ((nt*2+icc)*64 + lane)*8 + j ; k=(lane>>4)*8+j, oc=nt*16+(lane&15)
__global__ void pwxform_k(const float* __restrict__ src, _Float16* __restrict__ dst) {
    int id = blockIdx.x * 256 + threadIdx.x;
    if (id >= 32768) return;
    int j = id & 7, l = (id >> 3) & 63, icc = (id >> 9) & 1, nt = id >> 10;
    int kl = (l >> 4) * 8 + j, ic = icc * 32 + kl, oc = nt * 16 + (l & 15);
    float v = src[oc * 64 + ic];
    _Float16 hi = (_Float16)v;
    _Float16 lo = (_Float16)((v - (float)hi) * LO_SCALE);
    dst[id] = hi;
    dst[32768 + id] = lo;
}

// ---------------- conv1: 3->64, 64x64, pad1, +bias, relu, 2x2 maxpool.
// Output NHWC fp32 (B,32,32,64). Writes go through a padded LDS transpose
// buffer in 4 chunks of 16 oc -> fully coalesced 64B-line stores.
__global__ __launch_bounds__(256)
void conv1_k(const float* __restrict__ img, const float* __restrict__ w0t,
             const float* __restrict__ b0, float* __restrict__ out) {
    int b = blockIdx.x, tile = blockIdx.y;
    int typ = (tile >> 1) * 16, txp = (tile & 1) * 16;
    int cy0 = typ * 2, cx0 = txp * 2;
    __shared__ float lds[3][34][34];
    __shared__ float lo[256 * 17];  // [pixel][oc-chunk of 16], pad 17
    const float* imb = img + (size_t)b * 3 * 64 * 64;
    for (int i = threadIdx.x; i < 3 * 34 * 34; i += 256) {
        int c = i / 1156, rem = i % 1156, r = rem / 34, cc = rem % 34;
        int gy = cy0 - 1 + r, gx = cx0 - 1 + cc;
        float v = 0.f;
        if (gy >= 0 && gy < 64 && gx >= 0 && gx < 64) v = imb[(c * 64 + gy) * 64 + gx];
        lds[c][r][cc] = v;
    }
    __syncthreads();
    int pyl = threadIdx.x >> 4, pxl = threadIdx.x & 15;
    float win[3][4][4];
#pragma unroll
    for (int c = 0; c < 3; ++c)
#pragma unroll
        for (int wy = 0; wy < 4; ++wy)
#pragma unroll
            for (int wx = 0; wx < 4; ++wx)
                win[c][wy][wx] = lds[c][2 * pyl + wy][2 * pxl + wx];
    for (int ch = 0; ch < 4; ++ch) {
        __syncthreads();  // previous flush reads done
#pragma unroll
        for (int j = 0; j < 16; ++j) {
            int oc = ch * 16 + j;
            float a00 = 0, a01 = 0, a10 = 0, a11 = 0;
#pragma unroll
            for (int c = 0; c < 3; ++c)
#pragma unroll
                for (int ky = 0; ky < 3; ++ky)
#pragma unroll
                    for (int kx = 0; kx < 3; ++kx) {
                        float w = w0t[(c * 9 + ky * 3 + kx) * 64 + oc];
                        a00 = fmaf(win[c][0 + ky][0 + kx], w, a00);
                        a01 = fmaf(win[c][0 + ky][1 + kx], w, a01);
                        a10 = fmaf(win[c][1 + ky][0 + kx], w, a10);
                        a11 = fmaf(win[c][1 + ky][1 + kx], w, a11);
                    }
            float bv = b0[oc];
            float v = fmaxf(fmaxf(a00 + bv, 0.f), fmaxf(a01 + bv, 0.f));
            v = fmaxf(v, fmaxf(fmaxf(a10 + bv, 0.f), fmaxf(a11 + bv, 0.f)));
            lo[threadIdx.x * 17 + j] = v;
        }
        __syncthreads();
        // flush 256px x 16oc, coalesced
#pragma unroll
        for (int r = 0; r < 16; ++r) {
            int f = r * 256 + threadIdx.x;
            int pl = f >> 4, j = f & 15;
            int py = typ + (pl >> 4), px = txp + (pl & 15);
            out[(((size_t)b * 32 + py) * 32 + px) * 64 + ch * 16 + j] = lo[pl * 17 + j];
        }
    }
}

// ---------------- MFMA conv 64->64 3x3 pad1, NHWC fp32 in/out.
template <int S, bool POOL, bool RES>
__global__ __launch_bounds__(256, 2)
void convm_k(const float* __restrict__ in, float* __restrict__ out,
             const _Float16* __restrict__ wf, const float* __restrict__ bias,
             const float* __restrict__ res, const int* __restrict__ question,
             int qcol) {
    int b = blockIdx.x, t = blockIdx.y;
    constexpr int NTX = S / 16;
    int ty0 = (t / NTX) * 8, tx0 = (t % NTX) * 16;

    __shared__ __align__(16) _Float16 lds[2 * 7200];

    int tid = threadIdx.x, lane = tid & 63, wv = tid >> 6;
    const _Float16* wb = wf;
    const float* bb = bias;
    if (question) {
        int idx = question[b * 8 + qcol];
        wb += (size_t)idx * 73728;
        bb += idx * 64;
    }
    float bv[4];
#pragma unroll
    for (int nt = 0; nt < 4; ++nt) bv[nt] = bb[nt * 16 + (lane & 15)];

    f32x4 acc1[2][4] = {};
    f32x4 acc2[2][4] = {};

    int am = lane & 15;
    int k0 = (lane >> 4) * 8;

    for (int icc = 0; icc < 2; ++icc) {
        __syncthreads();
        for (int i = tid; i < 1440; i += 256) {
            int pix = i >> 3, j4 = i & 7;
            int hy = pix / 18, hx = pix % 18;
            int gy = ty0 + hy - 1, gx = tx0 + hx - 1;
            float4 v = {0.f, 0.f, 0.f, 0.f};
            if (gy >= 0 && gy < S && gx >= 0 && gx < S)
                v = *(const float4*)&in[(((size_t)b * S + gy) * S + gx) * 64 + icc * 32 + j4 * 4];
            _Float16 h0 = (_Float16)v.x, h1 = (_Float16)v.y;
            _Float16 h2 = (_Float16)v.z, h3 = (_Float16)v.w;
            half4_t hh = {h0, h1, h2, h3};
            half4_t ll = {(_Float16)((v.x - (float)h0) * LO_SCALE),
                          (_Float16)((v.y - (float)h1) * LO_SCALE),
                          (_Float16)((v.z - (float)h2) * LO_SCALE),
                          (_Float16)((v.w - (float)h3) * LO_SCALE)};
            *(half4_t*)&lds[pix * 40 + j4 * 4] = hh;
            *(half4_t*)&lds[7200 + pix * 40 + j4 * 4] = ll;
        }
        __syncthreads();

#pragma unroll
        for (int ky = 0; ky < 3; ++ky)
#pragma unroll
            for (int kx = 0; kx < 3; ++kx) {
                int tap = ky * 3 + kx;
                const _Float16* wp = wb + (tap * 2 + icc) * 2048 + lane * 8;
                half8 bhi[4], blo[4];
#pragma unroll
                for (int nt = 0; nt < 4; ++nt) {
                    bhi[nt] = *(const half8*)(wp + nt * 512);
                    blo[nt] = *(const half8*)(wp + nt * 512 + 36864);
                }
#pragma unroll
                for (int mt = 0; mt < 2; ++mt) {
                    int MT = wv * 2 + mt;
                    int Q = MT * 4 + (am >> 2), s = am & 3;
                    int py = (Q >> 3) * 2 + (s >> 1), px = (Q & 7) * 2 + (s & 1);
                    const _Float16* ap = &lds[((py + ky) * 18 + (px + kx)) * 40 + k0];
                    half8 ahi = *(const half8*)ap;
                    half8 alo = *(const half8*)(ap + 7200);
#pragma unroll
                    for (int nt = 0; nt < 4; ++nt) {
                        acc1[mt][nt] = __builtin_amdgcn_mfma_f32_16x16x32_f16(
                            ahi, bhi[nt], acc1[mt][nt], 0, 0, 0);
                        acc2[mt][nt] = __builtin_amdgcn_mfma_f32_16x16x32_f16(
                            ahi, blo[nt], acc2[mt][nt], 0, 0, 0);
                        acc2[mt][nt] = __builtin_amdgcn_mfma_f32_16x16x32_f16(
                            alo, bhi[nt], acc2[mt][nt], 0, 0, 0);
                    }
                }
            }
    }

    int cn = lane & 15, rq = lane >> 4;
#pragma unroll
    for (int mt = 0; mt < 2; ++mt) {
        int MT = wv * 2 + mt;
        int Q = MT * 4 + rq;
        int qy = Q >> 3, qx = Q & 7;
#pragma unroll
        for (int nt = 0; nt < 4; ++nt) {
            int oc = nt * 16 + cn;
            float vals[4];
#pragma unroll
            for (int r = 0; r < 4; ++r)
                vals[r] = acc1[mt][nt][r] + acc2[mt][nt][r] * LO_INV + bv[nt];
            if (POOL) {
                float m = fmaxf(fmaxf(vals[0], vals[1]), fmaxf(vals[2], vals[3]));
                m = fmaxf(m, 0.f);
                int opy = (ty0 >> 1) + qy, opx = (tx0 >> 1) + qx;
                out[(((size_t)b * (S / 2) + opy) * (S / 2) + opx) * 64 + oc] = m;
            } else {
#pragma unroll
                for (int r = 0; r < 4; ++r) {
                    int py = qy * 2 + (r >> 1), px = qx * 2 + (r & 1);
                    size_t o = (((size_t)b * S + (ty0 + py)) * S + (tx0 + px)) * 64 + oc;
                    float v = vals[r];
                    if (RES) v += res[o];
                    out[o] = fmaxf(v, 0.f);
                }
            }
        }
    }
}

// ---------------- proj (MFMA): per-sample GEMM C[256px][512oc], K=64, f16
// hi/lo. Quad-major M -> D-frag regs are a 2x2 pool window (in-lane pool).
// Pooled tile staged in padded LDS, flushed coalesced.
// Grid (256, 2): blockIdx.y selects 4 of the 8 oc-groups (64 oc each).
__global__ __launch_bounds__(256)
void projm_k(const float* __restrict__ in /*NHWC B,16,16,64*/,
             const _Float16* __restrict__ pw, const float* __restrict__ bias,
             float* __restrict__ out /* [B][512*64] */) {
    int b = blockIdx.x;
    __shared__ float lt[64 * 65];
    int tid = threadIdx.x, lane = tid & 63, wv = tid >> 6;
    int row = lane & 15, cseg = lane >> 4;

    // A fragments: wave handles Mtiles 4wv..4wv+3 (quad-major pixel order)
    half8 ah[4][2], al[4][2];
#pragma unroll
    for (int mt = 0; mt < 4; ++mt) {
        int MT = wv * 4 + mt;
        int Q = MT * 4 + (row >> 2), s = row & 3;
        int y = (Q >> 3) * 2 + (s >> 1), x = (Q & 7) * 2 + (s & 1);
        const float* ip = in + ((size_t)b * 256 + y * 16 + x) * 64 + cseg * 8;
#pragma unroll
        for (int icc = 0; icc < 2; ++icc) {
            float4 v0 = *(const float4*)(ip + icc * 32);
            float4 v1 = *(const float4*)(ip + icc * 32 + 4);
            _Float16 h0 = (_Float16)v0.x, h1 = (_Float16)v0.y;
            _Float16 h2 = (_Float16)v0.z, h3 = (_Float16)v0.w;
            _Float16 h4 = (_Float16)v1.x, h5 = (_Float16)v1.y;
            _Float16 h6 = (_Float16)v1.z, h7 = (_Float16)v1.w;
            ah[mt][icc] = (half8){h0, h1, h2, h3, h4, h5, h6, h7};
            al[mt][icc] = (half8){(_Float16)((v0.x - (float)h0) * LO_SCALE),
                                  (_Float16)((v0.y - (float)h1) * LO_SCALE),
                                  (_Float16)((v0.z - (float)h2) * LO_SCALE),
                                  (_Float16)((v0.w - (float)h3) * LO_SCALE),
                                  (_Float16)((v1.x - (float)h4) * LO_SCALE),
                                  (_Float16)((v1.y - (float)h5) * LO_SCALE),
                                  (_Float16)((v1.z - (float)h6) * LO_SCALE),
                                  (_Float16)((v1.w - (float)h7) * LO_SCALE)};
        }
    }

    for (int ogl = 0; ogl < 4; ++ogl) {
        int og = blockIdx.y * 4 + ogl;
        half8 bh[4][2], bl[4][2];
#pragma unroll
        for (int ntl = 0; ntl < 4; ++ntl)
#pragma unroll
            for (int icc = 0; icc < 2; ++icc) {
                int nt = og * 4 + ntl;
                const _Float16* wp = pw + ((nt * 2 + icc) * 64 + lane) * 8;
                bh[ntl][icc] = *(const half8*)wp;
                bl[ntl][icc] = *(const half8*)(wp + 32768);
            }
        f32x4 a1[4][4] = {};
        f32x4 a2[4][4] = {};
#pragma unroll
        for (int icc = 0; icc < 2; ++icc)
#pragma unroll
            for (int mt = 0; mt < 4; ++mt)
#pragma unroll
                for (int ntl = 0; ntl < 4; ++ntl) {
                    a1[mt][ntl] = __builtin_amdgcn_mfma_f32_16x16x32_f16(
                        ah[mt][icc], bh[ntl][icc], a1[mt][ntl], 0, 0, 0);
                    a2[mt][ntl] = __builtin_amdgcn_mfma_f32_16x16x32_f16(
                        ah[mt][icc], bl[ntl][icc], a2[mt][ntl], 0, 0, 0);
                    a2[mt][ntl] = __builtin_amdgcn_mfma_f32_16x16x32_f16(
                        al[mt][icc], bh[ntl][icc], a2[mt][ntl], 0, 0, 0);
                }
        if (ogl) __syncthreads();  // previous flush reads done before reuse
#pragma unroll
        for (int mt = 0; mt < 4; ++mt) {
            int Qg = (wv * 4 + mt) * 4 + (lane >> 4);
#pragma unroll
            for (int ntl = 0; ntl < 4; ++ntl) {
                float bvv = bias[og * 64 + ntl * 16 + (lane & 15)];
                float v0 = a1[mt][ntl][0] + a2[mt][ntl][0] * LO_INV + bvv;
                float v1 = a1[mt][ntl][1] + a2[mt][ntl][1] * LO_INV + bvv;
                float v2 = a1[mt][ntl][2] + a2[mt][ntl][2] * LO_INV + bvv;
                float v3 = a1[mt][ntl][3] + a2[mt][ntl][3] * LO_INV + bvv;
                float m = fmaxf(fmaxf(fmaxf(v0, v1), fmaxf(v2, v3)), 0.f);
                lt[(ntl * 16 + (lane & 15)) * 65 + Qg] = m;
            }
        }
        __syncthreads();
#pragma unroll
        for (int r = 0; r < 16; ++r) {
            int f = r * 256 + tid;
            int ol = f >> 6, q = f & 63;
            out[(size_t)b * 32768 + og * 4096 + ol * 64 + q] = lt[ol * 65 + q];
        }
    }
}

// ---------------- fc1 MFMA GEMM: C[256][1024] = A[256][32768] @ W[1024][32768]^T
__global__ __launch_bounds__(256)
void fc1m_k(const float* __restrict__ A, const float* __restrict__ W,
            float* __restrict__ partial /* [32][256][1024] */) {
    int bid = blockIdx.x;
    int lid = (bid & 7) * 64 + (bid >> 3);   // bijective, 512 % 8 == 0
    int mt = lid & 1, nt = (lid >> 1) & 7, ks = lid >> 4;
    int m0 = mt * 128, n0 = nt * 128;
    const float* Ab = A + (size_t)m0 * 32768 + ks * 1024;
    const float* Wb = W + (size_t)n0 * 32768 + ks * 1024;

    __shared__ __align__(16) _Float16 lds[20480];
    _Float16* sa = lds;
    _Float16* sb = lds + 10240;

    int tid = threadIdx.x, lane = tid & 63, wv = tid >> 6;
    int wm = (wv & 1) * 64, wn = (wv >> 1) * 64;

    f32x4 acc1[4][4] = {};
    f32x4 acc2[4][4] = {};

    int row[4], c4[4];
#pragma unroll
    for (int p = 0; p < 4; ++p) {
        int idx = p * 256 + tid;
        row[p] = idx >> 3;
        c4[p] = (idx & 7) << 2;
    }

    float4 ra[4], rw[4];
#pragma unroll
    for (int p = 0; p < 4; ++p) {
        ra[p] = *(const float4*)&Ab[(size_t)row[p] * 32768 + c4[p]];
        rw[p] = *(const float4*)&Wb[(size_t)row[p] * 32768 + c4[p]];
    }

    for (int kt = 0; kt < 32; ++kt) {
#pragma unroll
        for (int p = 0; p < 4; ++p) {
            float4 v = ra[p];
            _Float16 h0 = (_Float16)v.x, h1 = (_Float16)v.y;
            _Float16 h2 = (_Float16)v.z, h3 = (_Float16)v.w;
            half4_t hh = {h0, h1, h2, h3};
            half4_t ll = {(_Float16)((v.x - (float)h0) * LO_SCALE),
                          (_Float16)((v.y - (float)h1) * LO_SCALE),
                          (_Float16)((v.z - (float)h2) * LO_SCALE),
                          (_Float16)((v.w - (float)h3) * LO_SCALE)};
            *(half4_t*)&sa[row[p] * 40 + c4[p]] = hh;
            *(half4_t*)&sa[5120 + row[p] * 40 + c4[p]] = ll;
            float4 u = rw[p];
            _Float16 g0 = (_Float16)u.x, g1 = (_Float16)u.y;
            _Float16 g2 = (_Float16)u.z, g3 = (_Float16)u.w;
            half4_t gh = {g0, g1, g2, g3};
            half4_t gl = {(_Float16)((u.x - (float)g0) * LO_SCALE),
                          (_Float16)((u.y - (float)g1) * LO_SCALE),
                          (_Float16)((u.z - (float)g2) * LO_SCALE),
                          (_Float16)((u.w - (float)g3) * LO_SCALE)};
            *(half4_t*)&sb[row[p] * 40 + c4[p]] = gh;
            *(half4_t*)&sb[5120 + row[p] * 40 + c4[p]] = gl;
        }
        __syncthreads();
        if (kt < 31) {
            int kb = (kt + 1) * 32;
#pragma unroll
            for (int p = 0; p < 4; ++p) {
                ra[p] = *(const float4*)&Ab[(size_t)row[p] * 32768 + kb + c4[p]];
                rw[p] = *(const float4*)&Wb[(size_t)row[p] * 32768 + kb + c4[p]];
            }
        }
        int koff = (lane >> 4) * 8;
        int fr = lane & 15;
        half8 bh[4], bl[4];
#pragma unroll
        for (int nf = 0; nf < 4; ++nf) {
            int r = wn + nf * 16 + fr;
            bh[nf] = *(const half8*)&sb[r * 40 + koff];
            bl[nf] = *(const half8*)&sb[5120 + r * 40 + koff];
        }
#pragma unroll
        for (int mf = 0; mf < 4; ++mf) {
            int r = wm + mf * 16 + fr;
            half8 ah = *(const half8*)&sa[r * 40 + koff];
            half8 al = *(const half8*)&sa[5120 + r * 40 + koff];
#pragma unroll
            for (int nf = 0; nf < 4; ++nf) {
                acc1[mf][nf] = __builtin_amdgcn_mfma_f32_16x16x32_f16(
                    ah, bh[nf], acc1[mf][nf], 0, 0, 0);
                acc2[mf][nf] = __builtin_amdgcn_mfma_f32_16x16x32_f16(
                    ah, bl[nf], acc2[mf][nf], 0, 0, 0);
                acc2[mf][nf] = __builtin_amdgcn_mfma_f32_16x16x32_f16(
                    al, bh[nf], acc2[mf][nf], 0, 0, 0);
            }
        }
        __syncthreads();
    }

    int rq = lane >> 4, cn = lane & 15;
    float* pb = partial + (size_t)ks * 262144;
#pragma unroll
    for (int mf = 0; mf < 4; ++mf)
#pragma unroll
        for (int nf = 0; nf < 4; ++nf) {
            int n = n0 + wn + nf * 16 + cn;
#pragma unroll
            for (int r = 0; r < 4; ++r) {
                int m = m0 + wm + mf * 16 + rq * 4 + r;
                pb[(size_t)m * 1024 + n] = acc1[mf][nf][r] + acc2[mf][nf][r] * LO_INV;
            }
        }
}

__global__ __launch_bounds__(256)
void fc1red_k(const float* __restrict__ partial, const float* __restrict__ b1,
              float* __restrict__ fc1o_t /* [n][m] */) {
    int m = blockIdx.x;
    int n0 = threadIdx.x * 4;
    float4 s = {0.f, 0.f, 0.f, 0.f};
    for (int ks = 0; ks < 32; ++ks) {
        float4 v = *(const float4*)&partial[((size_t)ks * 256 + m) * 1024 + n0];
        s.x += v.x; s.y += v.y; s.z += v.z; s.w += v.w;
    }
    fc1o_t[(size_t)(n0 + 0) * 256 + m] = fmaxf(s.x + b1[n0 + 0], 0.f);
    fc1o_t[(size_t)(n0 + 1) * 256 + m] = fmaxf(s.y + b1[n0 + 1], 0.f);
    fc1o_t[(size_t)(n0 + 2) * 256 + m] = fmaxf(s.z + b1[n0 + 2], 0.f);
    fc1o_t[(size_t)(n0 + 3) * 256 + m] = fmaxf(s.w + b1[n0 + 3], 0.f);
}

__global__ __launch_bounds__(256)
void fc2a_k(const float* __restrict__ a_t, const float* __restrict__ W2,
            float* __restrict__ p2) {
    int n2 = blockIdx.x, ks = blockIdx.y;
    int m = threadIdx.x;
    float acc = 0.f;
    for (int k = ks * 256; k < ks * 256 + 256; ++k)
        acc = fmaf(a_t[(size_t)k * 256 + m], W2[n2 * 1024 + k], acc);
    p2[((size_t)n2 * 4 + ks) * 256 + m] = acc;
}

__global__ __launch_bounds__(512)
void fc2b_k(const float* __restrict__ p2, const float* __restrict__ b2,
            float* __restrict__ out) {
    int i = threadIdx.x;
    int m = i >> 1, n2 = i & 1;
    float s = b2[n2];
#pragma unroll
    for (int ks = 0; ks < 4; ++ks) s += p2[((size_t)n2 * 4 + ks) * 256 + m];
    out[m * 2 + n2] = s;
}

// ---------------------------------------------------------------------------
extern "C" void kernel_launch(void* const* d_in, const int* in_sizes, int n_in,
                              void* d_out, int out_size, void* d_ws, size_t ws_size,
                              hipStream_t stream) {
    const float* image   = (const float*)d_in[0];
    const int*   question= (const int*)d_in[1];
    const float* stem_w0 = (const float*)d_in[2];
    const float* stem_b0 = (const float*)d_in[3];
    const float* stem_w  = (const float*)d_in[4];
    const float* stem_b  = (const float*)d_in[5];
    const float* exp_w1  = (const float*)d_in[6];
    const float* exp_b1  = (const float*)d_in[7];
    const float* exp_w2  = (const float*)d_in[8];
    const float* exp_b2  = (const float*)d_in[9];
    const float* proj_w  = (const float*)d_in[10];
    const float* proj_b  = (const float*)d_in[11];
    const float* fc1_w   = (const float*)d_in[12];
    const float* fc1_b   = (const float*)d_in[13];
    const float* fc2_w   = (const float*)d_in[14];
    const float* fc2_b   = (const float*)d_in[15];
    (void)in_sizes; (void)n_in; (void)out_size; (void)ws_size;

    float* ws = (float*)d_ws;
    // Workspace (floats), peak ~156 MB:
    //  [0,A)        p1 NHWC (B,32,32,64); later hA/hB/hC (3*P2N); then fc1
    //               partials [32][256][1024]
    //  [A,2A)       h2 NHWC; later pool3 + fc1o
    //  [2A,2A+P2N)  p2 NHWC (B,16,16,64)
    //  [2A+P2N,..)  w0t | proj B-frag f16 | pfc2 | conv f16 weight planes
    const size_t A = 16777216, P2N = 4194304;
    float* p1    = ws;
    float* h2    = ws + A;
    float* p2    = ws + 2 * A;
    float* wtr   = ws + 2 * A + P2N;
    float* w0t   = wtr;                      // 1728 fp32
    _Float16* pwF = (_Float16*)(wtr + 1728); // 65536 f16 (= 32768 fp32 slots)
    float* pfc2  = wtr + 1728 + 32768;       // 2048 fp32
    _Float16* f16b = (_Float16*)(wtr + 36544);
    _Float16* stemtF = f16b;                 // 3 layers * 73728 f16
    _Float16* e1tF   = f16b + 3 * 73728;     // 16 layers
    _Float16* e2tF   = e1tF + 16 * 73728;    // 16 layers
    float* hA    = ws;
    float* hB    = ws + P2N;
    float* hC    = ws + 2 * P2N;
    float* pool3 = h2;
    float* fc1o  = h2 + 8388608;
    float* fc1p  = ws;

    // weight transforms
    transw_k<<<(1728 + 255) / 256, 256, 0, stream>>>(stem_w0, w0t, 64, 3, 9, 1728);
    pwxform_k<<<128, 256, 0, stream>>>(proj_w, pwF);
    wxform_k<<<(3 * 36864 + 255) / 256, 256, 0, stream>>>(stem_w, stemtF, 3);
    wxform_k<<<(16 * 36864 + 255) / 256, 256, 0, stream>>>(exp_w1, e1tF, 16);
    wxform_k<<<(16 * 36864 + 255) / 256, 256, 0, stream>>>(exp_w2, e2tF, 16);

    // stem
    conv1_k<<<dim3(256, 4), 256, 0, stream>>>(image, w0t, stem_b0, p1);
    convm_k<32, false, false><<<dim3(256, 8), 256, 0, stream>>>(
        p1, h2, stemtF, stem_b, nullptr, nullptr, 0);
    convm_k<32, true, false><<<dim3(256, 8), 256, 0, stream>>>(
        h2, p2, stemtF + 73728, stem_b + 64, nullptr, nullptr, 0);
    convm_k<16, false, false><<<dim3(256, 2), 256, 0, stream>>>(
        p2, hA, stemtF + 2 * 73728, stem_b + 128, nullptr, nullptr, 0);

    // expert residual rounds (cols 4,5,7)
    const int cols[3] = {4, 5, 7};
    float* hin = hA;
    float* hmid = hB;
    float* hout = hC;
    for (int r = 0; r < 3; ++r) {
        convm_k<16, false, false><<<dim3(256, 2), 256, 0, stream>>>(
            hin, hmid, e1tF, exp_b1, nullptr, question, cols[r]);
        convm_k<16, false, true><<<dim3(256, 2), 256, 0, stream>>>(
            hmid, hout, e2tF, exp_b2, hin, question, cols[r]);
        float* tp = hin; hin = hout; hout = hmid; hmid = tp;
    }
    // hin == final h (ws+0)

    // head
    projm_k<<<dim3(256, 2), 256, 0, stream>>>(hin, pwF, proj_b, pool3);
    fc1m_k<<<512, 256, 0, stream>>>(pool3, fc1_w, fc1p);
    fc1red_k<<<256, 256, 0, stream>>>(fc1p, fc1_b, fc1o);
    fc2a_k<<<dim3(2, 4), 256, 0, stream>>>(fc1o, fc2_w, pfc2);
    fc2b_k<<<1, 512, 0, stream>>>(pfc2, fc2_b, (float*)d_out);
}

// Round 7
// 486.548 us; speedup vs baseline: 1.2885x; 1.2885x over previous
//
#include <hip/hip_runtime.h>
#include <cstddef>

// ---------------------------------------------------------------------------
// SimpleModuleNet. B=256, D=64, E=16, H=W=64, PROJ=512, FC=1024, NA=2.
//
// R2: 64->64 convs on matrix pipe (mfma_f32_16x16x32_f16, f16 hi/lo split,
//     lo plane scaled 2048 -> ~2^-22 error). NHWC activations.
// R3: fc1 on matrix pipe (in-kernel hi/lo staging, 40-f16 LDS stride,
//     reg prefetch, XCD-bijective swizzle, split-K 32).
// R4: proj as per-sample MFMA GEMM with in-lane 2x2 pool + coalesced
//     LDS-transposed writes (fixed 8.6x write amplification).
// R5: conv1 regression fixed. R4's chunked conv1 caused the compiler (56
//     VGPR cap) to drop win[] from registers and re-read LDS per tap per oc
//     (~10x VALU bloat, 235us). Now: single pass, win in regs, oc chunks of
//     4 with uniform float4 s_load weights, float4 stores, no inner barriers.
// R6: resubmit of R5 (bench infra failure, no data).
// ---------------------------------------------------------------------------

typedef _Float16 half8 __attribute__((ext_vector_type(8)));
typedef _Float16 half4_t __attribute__((ext_vector_type(4)));
typedef float f32x4 __attribute__((ext_vector_type(4)));

#define LO_SCALE 2048.0f
#define LO_INV (1.0f / 2048.0f)

// ---------------- generic weight transpose  [o][i](KxK) -> [(i*K+k)][o]
__global__ void transw_k(const float* __restrict__ src, float* __restrict__ dst,
                         int O, int I, int K, int total) {
    int id = blockIdx.x * 256 + threadIdx.x;
    if (id >= total) return;
    int OIK = O * I * K;
    int n = id / OIK, rem = id % OIK;
    int o = rem / (I * K), r2 = rem % (I * K);
    int i = r2 / K, k = r2 % K;
    dst[(size_t)n * OIK + (i * K + k) * O + o] = src[id];
}

// ---------------- conv weight transform: [layer][oc=64][ic=64][3][3] fp32 ->
// f16 fragment layout: idx = (((tap*2+icc)*4+nt)*64 + lane)*8 + j
__global__ void wxform_k(const float* __restrict__ src, _Float16* __restrict__ dst,
                         int nlayers) {
    int id = blockIdx.x * 256 + threadIdx.x;
    if (id >= nlayers * 36864) return;
    int layer = id / 36864, idx = id % 36864;
    int j = idx & 7, l = (idx >> 3) & 63, nt = (idx >> 9) & 3;
    int icc = (idx >> 11) & 1, tap = idx >> 12;
    int kl = (l >> 4) * 8 + j, ic = icc * 32 + kl, oc = nt * 16 + (l & 15);
    float v = src[(size_t)layer * 36864 + (oc * 64 + ic) * 9 + tap];
    _Float16 hi = (_Float16)v;
    _Float16 lo = (_Float16)((v - (float)hi) * LO_SCALE);
    dst[(size_t)layer * 73728 + idx] = hi;
    dst[(size_t)layer * 73728 + 36864 + idx] = lo;
}

// ---------------- proj weight transform: [512 oc][64 ic] fp32 -> B-frag hi/lo
__global__ void pwxform_k(const float* __restrict__ src, _Float16* __restrict__ dst) {
    int id = blockIdx.x * 256 + threadIdx.x;
    if (id >= 32768) return;
    int j = id & 7, l = (id >> 3) & 63, icc = (id >> 9) & 1, nt = id >> 10;
    int kl = (l >> 4) * 8 + j, ic = icc * 32 + kl, oc = nt * 16 + (l & 15);
    float v = src[oc * 64 + ic];
    _Float16 hi = (_Float16)v;
    _Float16 lo = (_Float16)((v - (float)hi) * LO_SCALE);
    dst[id] = hi;
    dst[32768 + id] = lo;
}

// ---------------- conv1: 3->64, 64x64, pad1, +bias, relu, 2x2 maxpool.
// Output NHWC fp32 (B,32,32,64). One pooled pixel per thread; win[3][4][4]
// in registers for the WHOLE kernel (no barriers after load); oc in chunks
// of 4: 27 uniform float4 s_loads + 108 FMA + one float4 store per chunk.
__global__ __launch_bounds__(256)
void conv1_k(const float* __restrict__ img, const float* __restrict__ w0t,
             const float* __restrict__ b0, float* __restrict__ out) {
    int b = blockIdx.x, tile = blockIdx.y;
    int typ = (tile >> 1) * 16, txp = (tile & 1) * 16;
    int cy0 = typ * 2, cx0 = txp * 2;
    __shared__ float lds[3][34][34];
    const float* imb = img + (size_t)b * 3 * 64 * 64;
    for (int i = threadIdx.x; i < 3 * 34 * 34; i += 256) {
        int c = i / 1156, rem = i % 1156, r = rem / 34, cc = rem % 34;
        int gy = cy0 - 1 + r, gx = cx0 - 1 + cc;
        float v = 0.f;
        if (gy >= 0 && gy < 64 && gx >= 0 && gx < 64) v = imb[(c * 64 + gy) * 64 + gx];
        lds[c][r][cc] = v;
    }
    __syncthreads();
    int pyl = threadIdx.x >> 4, pxl = threadIdx.x & 15;
    float win[3][4][4];
#pragma unroll
    for (int c = 0; c < 3; ++c)
#pragma unroll
        for (int wy = 0; wy < 4; ++wy)
#pragma unroll
            for (int wx = 0; wx < 4; ++wx)
                win[c][wy][wx] = lds[c][2 * pyl + wy][2 * pxl + wx];
    int py = typ + pyl, px = txp + pxl;
    float* op = &out[(((size_t)b * 32 + py) * 32 + px) * 64];
    for (int ocq = 0; ocq < 16; ++ocq) {
        float acc[4][4] = {};  // [pool-pos][oc-lane]
#pragma unroll
        for (int c = 0; c < 3; ++c)
#pragma unroll
            for (int ky = 0; ky < 3; ++ky)
#pragma unroll
                for (int kx = 0; kx < 3; ++kx) {
                    float4 w = *(const float4*)&w0t[(c * 9 + ky * 3 + kx) * 64 + ocq * 4];
                    float wv4[4] = {w.x, w.y, w.z, w.w};
#pragma unroll
                    for (int p2 = 0; p2 < 4; ++p2) {
                        float iv = win[c][(p2 >> 1) + ky][(p2 & 1) + kx];
#pragma unroll
                        for (int o = 0; o < 4; ++o)
                            acc[p2][o] = fmaf(iv, wv4[o], acc[p2][o]);
                    }
                }
        float4 res;
        float* rp = (float*)&res;
#pragma unroll
        for (int o = 0; o < 4; ++o) {
            float bvv = b0[ocq * 4 + o];
            float m = fmaxf(fmaxf(acc[0][o], acc[1][o]), fmaxf(acc[2][o], acc[3][o]));
            rp[o] = fmaxf(m + bvv, 0.f);
        }
        *(float4*)&op[ocq * 4] = res;
    }
}

// ---------------- MFMA conv 64->64 3x3 pad1, NHWC fp32 in/out.
template <int S, bool POOL, bool RES>
__global__ __launch_bounds__(256, 2)
void convm_k(const float* __restrict__ in, float* __restrict__ out,
             const _Float16* __restrict__ wf, const float* __restrict__ bias,
             const float* __restrict__ res, const int* __restrict__ question,
             int qcol) {
    int b = blockIdx.x, t = blockIdx.y;
    constexpr int NTX = S / 16;
    int ty0 = (t / NTX) * 8, tx0 = (t % NTX) * 16;

    __shared__ __align__(16) _Float16 lds[2 * 7200];

    int tid = threadIdx.x, lane = tid & 63, wv = tid >> 6;
    const _Float16* wb = wf;
    const float* bb = bias;
    if (question) {
        int idx = question[b * 8 + qcol];
        wb += (size_t)idx * 73728;
        bb += idx * 64;
    }
    float bv[4];
#pragma unroll
    for (int nt = 0; nt < 4; ++nt) bv[nt] = bb[nt * 16 + (lane & 15)];

    f32x4 acc1[2][4] = {};
    f32x4 acc2[2][4] = {};

    int am = lane & 15;
    int k0 = (lane >> 4) * 8;

    for (int icc = 0; icc < 2; ++icc) {
        __syncthreads();
        for (int i = tid; i < 1440; i += 256) {
            int pix = i >> 3, j4 = i & 7;
            int hy = pix / 18, hx = pix % 18;
            int gy = ty0 + hy - 1, gx = tx0 + hx - 1;
            float4 v = {0.f, 0.f, 0.f, 0.f};
            if (gy >= 0 && gy < S && gx >= 0 && gx < S)
                v = *(const float4*)&in[(((size_t)b * S + gy) * S + gx) * 64 + icc * 32 + j4 * 4];
            _Float16 h0 = (_Float16)v.x, h1 = (_Float16)v.y;
            _Float16 h2 = (_Float16)v.z, h3 = (_Float16)v.w;
            half4_t hh = {h0, h1, h2, h3};
            half4_t ll = {(_Float16)((v.x - (float)h0) * LO_SCALE),
                          (_Float16)((v.y - (float)h1) * LO_SCALE),
                          (_Float16)((v.z - (float)h2) * LO_SCALE),
                          (_Float16)((v.w - (float)h3) * LO_SCALE)};
            *(half4_t*)&lds[pix * 40 + j4 * 4] = hh;
            *(half4_t*)&lds[7200 + pix * 40 + j4 * 4] = ll;
        }
        __syncthreads();

#pragma unroll
        for (int ky = 0; ky < 3; ++ky)
#pragma unroll
            for (int kx = 0; kx < 3; ++kx) {
                int tap = ky * 3 + kx;
                const _Float16* wp = wb + (tap * 2 + icc) * 2048 + lane * 8;
                half8 bhi[4], blo[4];
#pragma unroll
                for (int nt = 0; nt < 4; ++nt) {
                    bhi[nt] = *(const half8*)(wp + nt * 512);
                    blo[nt] = *(const half8*)(wp + nt * 512 + 36864);
                }
#pragma unroll
                for (int mt = 0; mt < 2; ++mt) {
                    int MT = wv * 2 + mt;
                    int Q = MT * 4 + (am >> 2), s = am & 3;
                    int py = (Q >> 3) * 2 + (s >> 1), px = (Q & 7) * 2 + (s & 1);
                    const _Float16* ap = &lds[((py + ky) * 18 + (px + kx)) * 40 + k0];
                    half8 ahi = *(const half8*)ap;
                    half8 alo = *(const half8*)(ap + 7200);
#pragma unroll
                    for (int nt = 0; nt < 4; ++nt) {
                        acc1[mt][nt] = __builtin_amdgcn_mfma_f32_16x16x32_f16(
                            ahi, bhi[nt], acc1[mt][nt], 0, 0, 0);
                        acc2[mt][nt] = __builtin_amdgcn_mfma_f32_16x16x32_f16(
                            ahi, blo[nt], acc2[mt][nt], 0, 0, 0);
                        acc2[mt][nt] = __builtin_amdgcn_mfma_f32_16x16x32_f16(
                            alo, bhi[nt], acc2[mt][nt], 0, 0, 0);
                    }
                }
            }
    }

    int cn = lane & 15, rq = lane >> 4;
#pragma unroll
    for (int mt = 0; mt < 2; ++mt) {
        int MT = wv * 2 + mt;
        int Q = MT * 4 + rq;
        int qy = Q >> 3, qx = Q & 7;
#pragma unroll
        for (int nt = 0; nt < 4; ++nt) {
            int oc = nt * 16 + cn;
            float vals[4];
#pragma unroll
            for (int r = 0; r < 4; ++r)
                vals[r] = acc1[mt][nt][r] + acc2[mt][nt][r] * LO_INV + bv[nt];
            if (POOL) {
                float m = fmaxf(fmaxf(vals[0], vals[1]), fmaxf(vals[2], vals[3]));
                m = fmaxf(m, 0.f);
                int opy = (ty0 >> 1) + qy, opx = (tx0 >> 1) + qx;
                out[(((size_t)b * (S / 2) + opy) * (S / 2) + opx) * 64 + oc] = m;
            } else {
#pragma unroll
                for (int r = 0; r < 4; ++r) {
                    int py = qy * 2 + (r >> 1), px = qx * 2 + (r & 1);
                    size_t o = (((size_t)b * S + (ty0 + py)) * S + (tx0 + px)) * 64 + oc;
                    float v = vals[r];
                    if (RES) v += res[o];
                    out[o] = fmaxf(v, 0.f);
                }
            }
        }
    }
}

// ---------------- proj (MFMA): per-sample GEMM C[256px][512oc], K=64, f16
// hi/lo. Quad-major M -> D-frag regs are a 2x2 pool window (in-lane pool).
__global__ __launch_bounds__(256)
void projm_k(const float* __restrict__ in /*NHWC B,16,16,64*/,
             const _Float16* __restrict__ pw, const float* __restrict__ bias,
             float* __restrict__ out /* [B][512*64] */) {
    int b = blockIdx.x;
    __shared__ float lt[64 * 65];
    int tid = threadIdx.x, lane = tid & 63, wv = tid >> 6;
    int row = lane & 15, cseg = lane >> 4;

    half8 ah[4][2], al[4][2];
#pragma unroll
    for (int mt = 0; mt < 4; ++mt) {
        int MT = wv * 4 + mt;
        int Q = MT * 4 + (row >> 2), s = row & 3;
        int y = (Q >> 3) * 2 + (s >> 1), x = (Q & 7) * 2 + (s & 1);
        const float* ip = in + ((size_t)b * 256 + y * 16 + x) * 64 + cseg * 8;
#pragma unroll
        for (int icc = 0; icc < 2; ++icc) {
            float4 v0 = *(const float4*)(ip + icc * 32);
            float4 v1 = *(const float4*)(ip + icc * 32 + 4);
            _Float16 h0 = (_Float16)v0.x, h1 = (_Float16)v0.y;
            _Float16 h2 = (_Float16)v0.z, h3 = (_Float16)v0.w;
            _Float16 h4 = (_Float16)v1.x, h5 = (_Float16)v1.y;
            _Float16 h6 = (_Float16)v1.z, h7 = (_Float16)v1.w;
            ah[mt][icc] = (half8){h0, h1, h2, h3, h4, h5, h6, h7};
            al[mt][icc] = (half8){(_Float16)((v0.x - (float)h0) * LO_SCALE),
                                  (_Float16)((v0.y - (float)h1) * LO_SCALE),
                                  (_Float16)((v0.z - (float)h2) * LO_SCALE),
                                  (_Float16)((v0.w - (float)h3) * LO_SCALE),
                                  (_Float16)((v1.x - (float)h4) * LO_SCALE),
                                  (_Float16)((v1.y - (float)h5) * LO_SCALE),
                                  (_Float16)((v1.z - (float)h6) * LO_SCALE),
                                  (_Float16)((v1.w - (float)h7) * LO_SCALE)};
        }
    }

    for (int ogl = 0; ogl < 4; ++ogl) {
        int og = blockIdx.y * 4 + ogl;
        half8 bh[4][2], bl[4][2];
#pragma unroll
        for (int ntl = 0; ntl < 4; ++ntl)
#pragma unroll
            for (int icc = 0; icc < 2; ++icc) {
                int nt = og * 4 + ntl;
                const _Float16* wp = pw + ((nt * 2 + icc) * 64 + lane) * 8;
                bh[ntl][icc] = *(const half8*)wp;
                bl[ntl][icc] = *(const half8*)(wp + 32768);
            }
        f32x4 a1[4][4] = {};
        f32x4 a2[4][4] = {};
#pragma unroll
        for (int icc = 0; icc < 2; ++icc)
#pragma unroll
            for (int mt = 0; mt < 4; ++mt)
#pragma unroll
                for (int ntl = 0; ntl < 4; ++ntl) {
                    a1[mt][ntl] = __builtin_amdgcn_mfma_f32_16x16x32_f16(
                        ah[mt][icc], bh[ntl][icc], a1[mt][ntl], 0, 0, 0);
                    a2[mt][ntl] = __builtin_amdgcn_mfma_f32_16x16x32_f16(
                        ah[mt][icc], bl[ntl][icc], a2[mt][ntl], 0, 0, 0);
                    a2[mt][ntl] = __builtin_amdgcn_mfma_f32_16x16x32_f16(
                        al[mt][icc], bh[ntl][icc], a2[mt][ntl], 0, 0, 0);
                }
        if (ogl) __syncthreads();
#pragma unroll
        for (int mt = 0; mt < 4; ++mt) {
            int Qg = (wv * 4 + mt) * 4 + (lane >> 4);
#pragma unroll
            for (int ntl = 0; ntl < 4; ++ntl) {
                float bvv = bias[og * 64 + ntl * 16 + (lane & 15)];
                float v0 = a1[mt][ntl][0] + a2[mt][ntl][0] * LO_INV + bvv;
                float v1 = a1[mt][ntl][1] + a2[mt][ntl][1] * LO_INV + bvv;
                float v2 = a1[mt][ntl][2] + a2[mt][ntl][2] * LO_INV + bvv;
                float v3 = a1[mt][ntl][3] + a2[mt][ntl][3] * LO_INV + bvv;
                float m = fmaxf(fmaxf(fmaxf(v0, v1), fmaxf(v2, v3)), 0.f);
                lt[(ntl * 16 + (lane & 15)) * 65 + Qg] = m;
            }
        }
        __syncthreads();
#pragma unroll
        for (int r = 0; r < 16; ++r) {
            int f = r * 256 + tid;
            int ol = f >> 6, q = f & 63;
            out[(size_t)b * 32768 + og * 4096 + ol * 64 + q] = lt[ol * 65 + q];
        }
    }
}

// ---------------- fc1 MFMA GEMM: C[256][1024] = A[256][32768] @ W[1024][32768]^T
__global__ __launch_bounds__(256)
void fc1m_k(const float* __restrict__ A, const float* __restrict__ W,
            float* __restrict__ partial /* [32][256][1024] */) {
    int bid = blockIdx.x;
    int lid = (bid & 7) * 64 + (bid >> 3);   // bijective, 512 % 8 == 0
    int mt = lid & 1, nt = (lid >> 1) & 7, ks = lid >> 4;
    int m0 = mt * 128, n0 = nt * 128;
    const float* Ab = A + (size_t)m0 * 32768 + ks * 1024;
    const float* Wb = W + (size_t)n0 * 32768 + ks * 1024;

    __shared__ __align__(16) _Float16 lds[20480];
    _Float16* sa = lds;
    _Float16* sb = lds + 10240;

    int tid = threadIdx.x, lane = tid & 63, wv = tid >> 6;
    int wm = (wv & 1) * 64, wn = (wv >> 1) * 64;

    f32x4 acc1[4][4] = {};
    f32x4 acc2[4][4] = {};

    int row[4], c4[4];
#pragma unroll
    for (int p = 0; p < 4; ++p) {
        int idx = p * 256 + tid;
        row[p] = idx >> 3;
        c4[p] = (idx & 7) << 2;
    }

    float4 ra[4], rw[4];
#pragma unroll
    for (int p = 0; p < 4; ++p) {
        ra[p] = *(const float4*)&Ab[(size_t)row[p] * 32768 + c4[p]];
        rw[p] = *(const float4*)&Wb[(size_t)row[p] * 32768 + c4[p]];
    }

    for (int kt = 0; kt < 32; ++kt) {
#pragma unroll
        for (int p = 0; p < 4; ++p) {
            float4 v = ra[p];
            _Float16 h0 = (_Float16)v.x, h1 = (_Float16)v.y;
            _Float16 h2 = (_Float16)v.z, h3 = (_Float16)v.w;
            half4_t hh = {h0, h1, h2, h3};
            half4_t ll = {(_Float16)((v.x - (float)h0) * LO_SCALE),
                          (_Float16)((v.y - (float)h1) * LO_SCALE),
                          (_Float16)((v.z - (float)h2) * LO_SCALE),
                          (_Float16)((v.w - (float)h3) * LO_SCALE)};
            *(half4_t*)&sa[row[p] * 40 + c4[p]] = hh;
            *(half4_t*)&sa[5120 + row[p] * 40 + c4[p]] = ll;
            float4 u = rw[p];
            _Float16 g0 = (_Float16)u.x, g1 = (_Float16)u.y;
            _Float16 g2 = (_Float16)u.z, g3 = (_Float16)u.w;
            half4_t gh = {g0, g1, g2, g3};
            half4_t gl = {(_Float16)((u.x - (float)g0) * LO_SCALE),
                          (_Float16)((u.y - (float)g1) * LO_SCALE),
                          (_Float16)((u.z - (float)g2) * LO_SCALE),
                          (_Float16)((u.w - (float)g3) * LO_SCALE)};
            *(half4_t*)&sb[row[p] * 40 + c4[p]] = gh;
            *(half4_t*)&sb[5120 + row[p] * 40 + c4[p]] = gl;
        }
        __syncthreads();
        if (kt < 31) {
            int kb = (kt + 1) * 32;
#pragma unroll
            for (int p = 0; p < 4; ++p) {
                ra[p] = *(const float4*)&Ab[(size_t)row[p] * 32768 + kb + c4[p]];
                rw[p] = *(const float4*)&Wb[(size_t)row[p] * 32768 + kb + c4[p]];
            }
        }
        int koff = (lane >> 4) * 8;
        int fr = lane & 15;
        half8 bh[4], bl[4];
#pragma unroll
        for (int nf = 0; nf < 4; ++nf) {
            int r = wn + nf * 16 + fr;
            bh[nf] = *(const half8*)&sb[r * 40 + koff];
            bl[nf] = *(const half8*)&sb[5120 + r * 40 + koff];
        }
#pragma unroll
        for (int mf = 0; mf < 4; ++mf) {
            int r = wm + mf * 16 + fr;
            half8 ah = *(const half8*)&sa[r * 40 + koff];
            half8 al = *(const half8*)&sa[5120 + r * 40 + koff];
#pragma unroll
            for (int nf = 0; nf < 4; ++nf) {
                acc1[mf][nf] = __builtin_amdgcn_mfma_f32_16x16x32_f16(
                    ah, bh[nf], acc1[mf][nf], 0, 0, 0);
                acc2[mf][nf] = __builtin_amdgcn_mfma_f32_16x16x32_f16(
                    ah, bl[nf], acc2[mf][nf], 0, 0, 0);
                acc2[mf][nf] = __builtin_amdgcn_mfma_f32_16x16x32_f16(
                    al, bh[nf], acc2[mf][nf], 0, 0, 0);
            }
        }
        __syncthreads();
    }

    int rq = lane >> 4, cn = lane & 15;
    float* pb = partial + (size_t)ks * 262144;
#pragma unroll
    for (int mf = 0; mf < 4; ++mf)
#pragma unroll
        for (int nf = 0; nf < 4; ++nf) {
            int n = n0 + wn + nf * 16 + cn;
#pragma unroll
            for (int r = 0; r < 4; ++r) {
                int m = m0 + wm + mf * 16 + rq * 4 + r;
                pb[(size_t)m * 1024 + n] = acc1[mf][nf][r] + acc2[mf][nf][r] * LO_INV;
            }
        }
}

__global__ __launch_bounds__(256)
void fc1red_k(const float* __restrict__ partial, const float* __restrict__ b1,
              float* __restrict__ fc1o_t /* [n][m] */) {
    int m = blockIdx.x;
    int n0 = threadIdx.x * 4;
    float4 s = {0.f, 0.f, 0.f, 0.f};
    for (int ks = 0; ks < 32; ++ks) {
        float4 v = *(const float4*)&partial[((size_t)ks * 256 + m) * 1024 + n0];
        s.x += v.x; s.y += v.y; s.z += v.z; s.w += v.w;
    }
    fc1o_t[(size_t)(n0 + 0) * 256 + m] = fmaxf(s.x + b1[n0 + 0], 0.f);
    fc1o_t[(size_t)(n0 + 1) * 256 + m] = fmaxf(s.y + b1[n0 + 1], 0.f);
    fc1o_t[(size_t)(n0 + 2) * 256 + m] = fmaxf(s.z + b1[n0 + 2], 0.f);
    fc1o_t[(size_t)(n0 + 3) * 256 + m] = fmaxf(s.w + b1[n0 + 3], 0.f);
}

__global__ __launch_bounds__(256)
void fc2a_k(const float* __restrict__ a_t, const float* __restrict__ W2,
            float* __restrict__ p2) {
    int n2 = blockIdx.x, ks = blockIdx.y;
    int m = threadIdx.x;
    float acc = 0.f;
    for (int k = ks * 256; k < ks * 256 + 256; ++k)
        acc = fmaf(a_t[(size_t)k * 256 + m], W2[n2 * 1024 + k], acc);
    p2[((size_t)n2 * 4 + ks) * 256 + m] = acc;
}

__global__ __launch_bounds__(512)
void fc2b_k(const float* __restrict__ p2, const float* __restrict__ b2,
            float* __restrict__ out) {
    int i = threadIdx.x;
    int m = i >> 1, n2 = i & 1;
    float s = b2[n2];
#pragma unroll
    for (int ks = 0; ks < 4; ++ks) s += p2[((size_t)n2 * 4 + ks) * 256 + m];
    out[m * 2 + n2] = s;
}

// ---------------------------------------------------------------------------
extern "C" void kernel_launch(void* const* d_in, const int* in_sizes, int n_in,
                              void* d_out, int out_size, void* d_ws, size_t ws_size,
                              hipStream_t stream) {
    const float* image   = (const float*)d_in[0];
    const int*   question= (const int*)d_in[1];
    const float* stem_w0 = (const float*)d_in[2];
    const float* stem_b0 = (const float*)d_in[3];
    const float* stem_w  = (const float*)d_in[4];
    const float* stem_b  = (const float*)d_in[5];
    const float* exp_w1  = (const float*)d_in[6];
    const float* exp_b1  = (const float*)d_in[7];
    const float* exp_w2  = (const float*)d_in[8];
    const float* exp_b2  = (const float*)d_in[9];
    const float* proj_w  = (const float*)d_in[10];
    const float* proj_b  = (const float*)d_in[11];
    const float* fc1_w   = (const float*)d_in[12];
    const float* fc1_b   = (const float*)d_in[13];
    const float* fc2_w   = (const float*)d_in[14];
    const float* fc2_b   = (const float*)d_in[15];
    (void)in_sizes; (void)n_in; (void)out_size; (void)ws_size;

    float* ws = (float*)d_ws;
    const size_t A = 16777216, P2N = 4194304;
    float* p1    = ws;
    float* h2    = ws + A;
    float* p2    = ws + 2 * A;
    float* wtr   = ws + 2 * A + P2N;
    float* w0t   = wtr;                      // 1728 fp32
    _Float16* pwF = (_Float16*)(wtr + 1728); // 65536 f16
    float* pfc2  = wtr + 1728 + 32768;       // 2048 fp32
    _Float16* f16b = (_Float16*)(wtr + 36544);
    _Float16* stemtF = f16b;                 // 3 layers * 73728 f16
    _Float16* e1tF   = f16b + 3 * 73728;     // 16 layers
    _Float16* e2tF   = e1tF + 16 * 73728;    // 16 layers
    float* hA    = ws;
    float* hB    = ws + P2N;
    float* hC    = ws + 2 * P2N;
    float* pool3 = h2;
    float* fc1o  = h2 + 8388608;
    float* fc1p  = ws;

    // weight transforms
    transw_k<<<(1728 + 255) / 256, 256, 0, stream>>>(stem_w0, w0t, 64, 3, 9, 1728);
    pwxform_k<<<128, 256, 0, stream>>>(proj_w, pwF);
    wxform_k<<<(3 * 36864 + 255) / 256, 256, 0, stream>>>(stem_w, stemtF, 3);
    wxform_k<<<(16 * 36864 + 255) / 256, 256, 0, stream>>>(exp_w1, e1tF, 16);
    wxform_k<<<(16 * 36864 + 255) / 256, 256, 0, stream>>>(exp_w2, e2tF, 16);

    // stem
    conv1_k<<<dim3(256, 4), 256, 0, stream>>>(image, w0t, stem_b0, p1);
    convm_k<32, false, false><<<dim3(256, 8), 256, 0, stream>>>(
        p1, h2, stemtF, stem_b, nullptr, nullptr, 0);
    convm_k<32, true, false><<<dim3(256, 8), 256, 0, stream>>>(
        h2, p2, stemtF + 73728, stem_b + 64, nullptr, nullptr, 0);
    convm_k<16, false, false><<<dim3(256, 2), 256, 0, stream>>>(
        p2, hA, stemtF + 2 * 73728, stem_b + 128, nullptr, nullptr, 0);

    // expert residual rounds (cols 4,5,7)
    const int cols[3] = {4, 5, 7};
    float* hin = hA;
    float* hmid = hB;
    float* hout = hC;
    for (int r = 0; r < 3; ++r) {
        convm_k<16, false, false><<<dim3(256, 2), 256, 0, stream>>>(
            hin, hmid, e1tF, exp_b1, nullptr, question, cols[r]);
        convm_k<16, false, true><<<dim3(256, 2), 256, 0, stream>>>(
            hmid, hout, e2tF, exp_b2, hin, question, cols[r]);
        float* tp = hin; hin = hout; hout = hmid; hmid = tp;
    }
    // hin == final h (ws+0)

    // head
    projm_k<<<dim3(256, 2), 256, 0, stream>>>(hin, pwF, proj_b, pool3);
    fc1m_k<<<512, 256, 0, stream>>>(pool3, fc1_w, fc1p);
    fc1red_k<<<256, 256, 0, stream>>>(fc1p, fc1_b, fc1o);
    fc2a_k<<<dim3(2, 4), 256, 0, stream>>>(fc1o, fc2_w, pfc2);
    fc2b_k<<<1, 512, 0, stream>>>(pfc2, fc2_b, (float*)d_out);
}

// Round 9
// 463.909 us; speedup vs baseline: 1.3514x; 1.0488x over previous
//
#include <hip/hip_runtime.h>
#include <cstddef>

// ---------------------------------------------------------------------------
// SimpleModuleNet. B=256, D=64, E=16, H=W=64, PROJ=512, FC=1024, NA=2.
//
// R2: 64->64 convs on matrix pipe (mfma_f32_16x16x32_f16, f16 hi/lo split,
//     lo plane scaled 2048 -> ~2^-22 error). NHWC activations.
// R3: fc1 on matrix pipe (in-kernel hi/lo staging, 40-f16 LDS stride,
//     reg prefetch, XCD-bijective swizzle, split-K 32).
// R4: proj as per-sample MFMA GEMM with in-lane 2x2 pool + coalesced
//     LDS-transposed writes (fixed 8.6x write amplification).
// R5: conv1: single pass, win[] in regs, uniform float4 s_load weights.
// R7: conv1 was latency-bound at 25% occupancy (1024 blocks only, VALU 45%).
//     Split oc across blockIdx.z (grid 256x4x4, 16384 waves): 4 oc-quads per
//     block, staging replicated (L2-resident). Expect ~2x on conv1.
// R8: resubmit of R7 (bench infra failure, no data).
// ---------------------------------------------------------------------------

typedef _Float16 half8 __attribute__((ext_vector_type(8)));
typedef _Float16 half4_t __attribute__((ext_vector_type(4)));
typedef float f32x4 __attribute__((ext_vector_type(4)));

#define LO_SCALE 2048.0f
#define LO_INV (1.0f / 2048.0f)

// ---------------- generic weight transpose  [o][i](KxK) -> [(i*K+k)][o]
__global__ void transw_k(const float* __restrict__ src, float* __restrict__ dst,
                         int O, int I, int K, int total) {
    int id = blockIdx.x * 256 + threadIdx.x;
    if (id >= total) return;
    int OIK = O * I * K;
    int n = id / OIK, rem = id % OIK;
    int o = rem / (I * K), r2 = rem % (I * K);
    int i = r2 / K, k = r2 % K;
    dst[(size_t)n * OIK + (i * K + k) * O + o] = src[id];
}

// ---------------- conv weight transform: [layer][oc=64][ic=64][3][3] fp32 ->
// f16 fragment layout: idx = (((tap*2+icc)*4+nt)*64 + lane)*8 + j
__global__ void wxform_k(const float* __restrict__ src, _Float16* __restrict__ dst,
                         int nlayers) {
    int id = blockIdx.x * 256 + threadIdx.x;
    if (id >= nlayers * 36864) return;
    int layer = id / 36864, idx = id % 36864;
    int j = idx & 7, l = (idx >> 3) & 63, nt = (idx >> 9) & 3;
    int icc = (idx >> 11) & 1, tap = idx >> 12;
    int kl = (l >> 4) * 8 + j, ic = icc * 32 + kl, oc = nt * 16 + (l & 15);
    float v = src[(size_t)layer * 36864 + (oc * 64 + ic) * 9 + tap];
    _Float16 hi = (_Float16)v;
    _Float16 lo = (_Float16)((v - (float)hi) * LO_SCALE);
    dst[(size_t)layer * 73728 + idx] = hi;
    dst[(size_t)layer * 73728 + 36864 + idx] = lo;
}

// ---------------- proj weight transform: [512 oc][64 ic] fp32 -> B-frag hi/lo
__global__ void pwxform_k(const float* __restrict__ src, _Float16* __restrict__ dst) {
    int id = blockIdx.x * 256 + threadIdx.x;
    if (id >= 32768) return;
    int j = id & 7, l = (id >> 3) & 63, icc = (id >> 9) & 1, nt = id >> 10;
    int kl = (l >> 4) * 8 + j, ic = icc * 32 + kl, oc = nt * 16 + (l & 15);
    float v = src[oc * 64 + ic];
    _Float16 hi = (_Float16)v;
    _Float16 lo = (_Float16)((v - (float)hi) * LO_SCALE);
    dst[id] = hi;
    dst[32768 + id] = lo;
}

// ---------------- conv1: 3->64, 64x64, pad1, +bias, relu, 2x2 maxpool.
// Output NHWC fp32 (B,32,32,64). Grid (b, tile, ocg): each block computes 16
// of the 64 oc for a 16x16 pooled tile. win[3][4][4] register-resident, no
// inner barriers; weights via uniform float4 s_load; float4 stores.
__global__ __launch_bounds__(256)
void conv1_k(const float* __restrict__ img, const float* __restrict__ w0t,
             const float* __restrict__ b0, float* __restrict__ out) {
    int b = blockIdx.x, tile = blockIdx.y, ocg = blockIdx.z;
    int typ = (tile >> 1) * 16, txp = (tile & 1) * 16;
    int cy0 = typ * 2, cx0 = txp * 2;
    __shared__ float lds[3][34][34];
    const float* imb = img + (size_t)b * 3 * 64 * 64;
    for (int i = threadIdx.x; i < 3 * 34 * 34; i += 256) {
        int c = i / 1156, rem = i % 1156, r = rem / 34, cc = rem % 34;
        int gy = cy0 - 1 + r, gx = cx0 - 1 + cc;
        float v = 0.f;
        if (gy >= 0 && gy < 64 && gx >= 0 && gx < 64) v = imb[(c * 64 + gy) * 64 + gx];
        lds[c][r][cc] = v;
    }
    __syncthreads();
    int pyl = threadIdx.x >> 4, pxl = threadIdx.x & 15;
    float win[3][4][4];
#pragma unroll
    for (int c = 0; c < 3; ++c)
#pragma unroll
        for (int wy = 0; wy < 4; ++wy)
#pragma unroll
            for (int wx = 0; wx < 4; ++wx)
                win[c][wy][wx] = lds[c][2 * pyl + wy][2 * pxl + wx];
    int py = typ + pyl, px = txp + pxl;
    float* op = &out[(((size_t)b * 32 + py) * 32 + px) * 64];
#pragma unroll
    for (int q = 0; q < 4; ++q) {
        int ocq = ocg * 4 + q;
        float acc[4][4] = {};  // [pool-pos][oc-lane]
#pragma unroll
        for (int c = 0; c < 3; ++c)
#pragma unroll
            for (int ky = 0; ky < 3; ++ky)
#pragma unroll
                for (int kx = 0; kx < 3; ++kx) {
                    float4 w = *(const float4*)&w0t[(c * 9 + ky * 3 + kx) * 64 + ocq * 4];
                    float wv4[4] = {w.x, w.y, w.z, w.w};
#pragma unroll
                    for (int p2 = 0; p2 < 4; ++p2) {
                        float iv = win[c][(p2 >> 1) + ky][(p2 & 1) + kx];
#pragma unroll
                        for (int o = 0; o < 4; ++o)
                            acc[p2][o] = fmaf(iv, wv4[o], acc[p2][o]);
                    }
                }
        float4 res;
        float* rp = (float*)&res;
#pragma unroll
        for (int o = 0; o < 4; ++o) {
            float bvv = b0[ocq * 4 + o];
            float m = fmaxf(fmaxf(acc[0][o], acc[1][o]), fmaxf(acc[2][o], acc[3][o]));
            rp[o] = fmaxf(m + bvv, 0.f);
        }
        *(float4*)&op[ocq * 4] = res;
    }
}

// ---------------- MFMA conv 64->64 3x3 pad1, NHWC fp32 in/out.
template <int S, bool POOL, bool RES>
__global__ __launch_bounds__(256, 2)
void convm_k(const float* __restrict__ in, float* __restrict__ out,
             const _Float16* __restrict__ wf, const float* __restrict__ bias,
             const float* __restrict__ res, const int* __restrict__ question,
             int qcol) {
    int b = blockIdx.x, t = blockIdx.y;
    constexpr int NTX = S / 16;
    int ty0 = (t / NTX) * 8, tx0 = (t % NTX) * 16;

    __shared__ __align__(16) _Float16 lds[2 * 7200];

    int tid = threadIdx.x, lane = tid & 63, wv = tid >> 6;
    const _Float16* wb = wf;
    const float* bb = bias;
    if (question) {
        int idx = question[b * 8 + qcol];
        wb += (size_t)idx * 73728;
        bb += idx * 64;
    }
    float bv[4];
#pragma unroll
    for (int nt = 0; nt < 4; ++nt) bv[nt] = bb[nt * 16 + (lane & 15)];

    f32x4 acc1[2][4] = {};
    f32x4 acc2[2][4] = {};

    int am = lane & 15;
    int k0 = (lane >> 4) * 8;

    for (int icc = 0; icc < 2; ++icc) {
        __syncthreads();
        for (int i = tid; i < 1440; i += 256) {
            int pix = i >> 3, j4 = i & 7;
            int hy = pix / 18, hx = pix % 18;
            int gy = ty0 + hy - 1, gx = tx0 + hx - 1;
            float4 v = {0.f, 0.f, 0.f, 0.f};
            if (gy >= 0 && gy < S && gx >= 0 && gx < S)
                v = *(const float4*)&in[(((size_t)b * S + gy) * S + gx) * 64 + icc * 32 + j4 * 4];
            _Float16 h0 = (_Float16)v.x, h1 = (_Float16)v.y;
            _Float16 h2 = (_Float16)v.z, h3 = (_Float16)v.w;
            half4_t hh = {h0, h1, h2, h3};
            half4_t ll = {(_Float16)((v.x - (float)h0) * LO_SCALE),
                          (_Float16)((v.y - (float)h1) * LO_SCALE),
                          (_Float16)((v.z - (float)h2) * LO_SCALE),
                          (_Float16)((v.w - (float)h3) * LO_SCALE)};
            *(half4_t*)&lds[pix * 40 + j4 * 4] = hh;
            *(half4_t*)&lds[7200 + pix * 40 + j4 * 4] = ll;
        }
        __syncthreads();

#pragma unroll
        for (int ky = 0; ky < 3; ++ky)
#pragma unroll
            for (int kx = 0; kx < 3; ++kx) {
                int tap = ky * 3 + kx;
                const _Float16* wp = wb + (tap * 2 + icc) * 2048 + lane * 8;
                half8 bhi[4], blo[4];
#pragma unroll
                for (int nt = 0; nt < 4; ++nt) {
                    bhi[nt] = *(const half8*)(wp + nt * 512);
                    blo[nt] = *(const half8*)(wp + nt * 512 + 36864);
                }
#pragma unroll
                for (int mt = 0; mt < 2; ++mt) {
                    int MT = wv * 2 + mt;
                    int Q = MT * 4 + (am >> 2), s = am & 3;
                    int py = (Q >> 3) * 2 + (s >> 1), px = (Q & 7) * 2 + (s & 1);
                    const _Float16* ap = &lds[((py + ky) * 18 + (px + kx)) * 40 + k0];
                    half8 ahi = *(const half8*)ap;
                    half8 alo = *(const half8*)(ap + 7200);
#pragma unroll
                    for (int nt = 0; nt < 4; ++nt) {
                        acc1[mt][nt] = __builtin_amdgcn_mfma_f32_16x16x32_f16(
                            ahi, bhi[nt], acc1[mt][nt], 0, 0, 0);
                        acc2[mt][nt] = __builtin_amdgcn_mfma_f32_16x16x32_f16(
                            ahi, blo[nt], acc2[mt][nt], 0, 0, 0);
                        acc2[mt][nt] = __builtin_amdgcn_mfma_f32_16x16x32_f16(
                            alo, bhi[nt], acc2[mt][nt], 0, 0, 0);
                    }
                }
            }
    }

    int cn = lane & 15, rq = lane >> 4;
#pragma unroll
    for (int mt = 0; mt < 2; ++mt) {
        int MT = wv * 2 + mt;
        int Q = MT * 4 + rq;
        int qy = Q >> 3, qx = Q & 7;
#pragma unroll
        for (int nt = 0; nt < 4; ++nt) {
            int oc = nt * 16 + cn;
            float vals[4];
#pragma unroll
            for (int r = 0; r < 4; ++r)
                vals[r] = acc1[mt][nt][r] + acc2[mt][nt][r] * LO_INV + bv[nt];
            if (POOL) {
                float m = fmaxf(fmaxf(vals[0], vals[1]), fmaxf(vals[2], vals[3]));
                m = fmaxf(m, 0.f);
                int opy = (ty0 >> 1) + qy, opx = (tx0 >> 1) + qx;
                out[(((size_t)b * (S / 2) + opy) * (S / 2) + opx) * 64 + oc] = m;
            } else {
#pragma unroll
                for (int r = 0; r < 4; ++r) {
                    int py = qy * 2 + (r >> 1), px = qx * 2 + (r & 1);
                    size_t o = (((size_t)b * S + (ty0 + py)) * S + (tx0 + px)) * 64 + oc;
                    float v = vals[r];
                    if (RES) v += res[o];
                    out[o] = fmaxf(v, 0.f);
                }
            }
        }
    }
}

// ---------------- proj (MFMA): per-sample GEMM C[256px][512oc], K=64, f16
// hi/lo. Quad-major M -> D-frag regs are a 2x2 pool window (in-lane pool).
__global__ __launch_bounds__(256)
void projm_k(const float* __restrict__ in /*NHWC B,16,16,64*/,
             const _Float16* __restrict__ pw, const float* __restrict__ bias,
             float* __restrict__ out /* [B][512*64] */) {
    int b = blockIdx.x;
    __shared__ float lt[64 * 65];
    int tid = threadIdx.x, lane = tid & 63, wv = tid >> 6;
    int row = lane & 15, cseg = lane >> 4;

    half8 ah[4][2], al[4][2];
#pragma unroll
    for (int mt = 0; mt < 4; ++mt) {
        int MT = wv * 4 + mt;
        int Q = MT * 4 + (row >> 2), s = row & 3;
        int y = (Q >> 3) * 2 + (s >> 1), x = (Q & 7) * 2 + (s & 1);
        const float* ip = in + ((size_t)b * 256 + y * 16 + x) * 64 + cseg * 8;
#pragma unroll
        for (int icc = 0; icc < 2; ++icc) {
            float4 v0 = *(const float4*)(ip + icc * 32);
            float4 v1 = *(const float4*)(ip + icc * 32 + 4);
            _Float16 h0 = (_Float16)v0.x, h1 = (_Float16)v0.y;
            _Float16 h2 = (_Float16)v0.z, h3 = (_Float16)v0.w;
            _Float16 h4 = (_Float16)v1.x, h5 = (_Float16)v1.y;
            _Float16 h6 = (_Float16)v1.z, h7 = (_Float16)v1.w;
            ah[mt][icc] = (half8){h0, h1, h2, h3, h4, h5, h6, h7};
            al[mt][icc] = (half8){(_Float16)((v0.x - (float)h0) * LO_SCALE),
                                  (_Float16)((v0.y - (float)h1) * LO_SCALE),
                                  (_Float16)((v0.z - (float)h2) * LO_SCALE),
                                  (_Float16)((v0.w - (float)h3) * LO_SCALE),
                                  (_Float16)((v1.x - (float)h4) * LO_SCALE),
                                  (_Float16)((v1.y - (float)h5) * LO_SCALE),
                                  (_Float16)((v1.z - (float)h6) * LO_SCALE),
                                  (_Float16)((v1.w - (float)h7) * LO_SCALE)};
        }
    }

    for (int ogl = 0; ogl < 4; ++ogl) {
        int og = blockIdx.y * 4 + ogl;
        half8 bh[4][2], bl[4][2];
#pragma unroll
        for (int ntl = 0; ntl < 4; ++ntl)
#pragma unroll
            for (int icc = 0; icc < 2; ++icc) {
                int nt = og * 4 + ntl;
                const _Float16* wp = pw + ((nt * 2 + icc) * 64 + lane) * 8;
                bh[ntl][icc] = *(const half8*)wp;
                bl[ntl][icc] = *(const half8*)(wp + 32768);
            }
        f32x4 a1[4][4] = {};
        f32x4 a2[4][4] = {};
#pragma unroll
        for (int icc = 0; icc < 2; ++icc)
#pragma unroll
            for (int mt = 0; mt < 4; ++mt)
#pragma unroll
                for (int ntl = 0; ntl < 4; ++ntl) {
                    a1[mt][ntl] = __builtin_amdgcn_mfma_f32_16x16x32_f16(
                        ah[mt][icc], bh[ntl][icc], a1[mt][ntl], 0, 0, 0);
                    a2[mt][ntl] = __builtin_amdgcn_mfma_f32_16x16x32_f16(
                        ah[mt][icc], bl[ntl][icc], a2[mt][ntl], 0, 0, 0);
                    a2[mt][ntl] = __builtin_amdgcn_mfma_f32_16x16x32_f16(
                        al[mt][icc], bh[ntl][icc], a2[mt][ntl], 0, 0, 0);
                }
        if (ogl) __syncthreads();
#pragma unroll
        for (int mt = 0; mt < 4; ++mt) {
            int Qg = (wv * 4 + mt) * 4 + (lane >> 4);
#pragma unroll
            for (int ntl = 0; ntl < 4; ++ntl) {
                float bvv = bias[og * 64 + ntl * 16 + (lane & 15)];
                float v0 = a1[mt][ntl][0] + a2[mt][ntl][0] * LO_INV + bvv;
                float v1 = a1[mt][ntl][1] + a2[mt][ntl][1] * LO_INV + bvv;
                float v2 = a1[mt][ntl][2] + a2[mt][ntl][2] * LO_INV + bvv;
                float v3 = a1[mt][ntl][3] + a2[mt][ntl][3] * LO_INV + bvv;
                float m = fmaxf(fmaxf(fmaxf(v0, v1), fmaxf(v2, v3)), 0.f);
                lt[(ntl * 16 + (lane & 15)) * 65 + Qg] = m;
            }
        }
        __syncthreads();
#pragma unroll
        for (int r = 0; r < 16; ++r) {
            int f = r * 256 + tid;
            int ol = f >> 6, q = f & 63;
            out[(size_t)b * 32768 + og * 4096 + ol * 64 + q] = lt[ol * 65 + q];
        }
    }
}

// ---------------- fc1 MFMA GEMM: C[256][1024] = A[256][32768] @ W[1024][32768]^T
__global__ __launch_bounds__(256)
void fc1m_k(const float* __restrict__ A, const float* __restrict__ W,
            float* __restrict__ partial /* [32][256][1024] */) {
    int bid = blockIdx.x;
    int lid = (bid & 7) * 64 + (bid >> 3);   // bijective, 512 % 8 == 0
    int mt = lid & 1, nt = (lid >> 1) & 7, ks = lid >> 4;
    int m0 = mt * 128, n0 = nt * 128;
    const float* Ab = A + (size_t)m0 * 32768 + ks * 1024;
    const float* Wb = W + (size_t)n0 * 32768 + ks * 1024;

    __shared__ __align__(16) _Float16 lds[20480];
    _Float16* sa = lds;
    _Float16* sb = lds + 10240;

    int tid = threadIdx.x, lane = tid & 63, wv = tid >> 6;
    int wm = (wv & 1) * 64, wn = (wv >> 1) * 64;

    f32x4 acc1[4][4] = {};
    f32x4 acc2[4][4] = {};

    int row[4], c4[4];
#pragma unroll
    for (int p = 0; p < 4; ++p) {
        int idx = p * 256 + tid;
        row[p] = idx >> 3;
        c4[p] = (idx & 7) << 2;
    }

    float4 ra[4], rw[4];
#pragma unroll
    for (int p = 0; p < 4; ++p) {
        ra[p] = *(const float4*)&Ab[(size_t)row[p] * 32768 + c4[p]];
        rw[p] = *(const float4*)&Wb[(size_t)row[p] * 32768 + c4[p]];
    }

    for (int kt = 0; kt < 32; ++kt) {
#pragma unroll
        for (int p = 0; p < 4; ++p) {
            float4 v = ra[p];
            _Float16 h0 = (_Float16)v.x, h1 = (_Float16)v.y;
            _Float16 h2 = (_Float16)v.z, h3 = (_Float16)v.w;
            half4_t hh = {h0, h1, h2, h3};
            half4_t ll = {(_Float16)((v.x - (float)h0) * LO_SCALE),
                          (_Float16)((v.y - (float)h1) * LO_SCALE),
                          (_Float16)((v.z - (float)h2) * LO_SCALE),
                          (_Float16)((v.w - (float)h3) * LO_SCALE)};
            *(half4_t*)&sa[row[p] * 40 + c4[p]] = hh;
            *(half4_t*)&sa[5120 + row[p] * 40 + c4[p]] = ll;
            float4 u = rw[p];
            _Float16 g0 = (_Float16)u.x, g1 = (_Float16)u.y;
            _Float16 g2 = (_Float16)u.z, g3 = (_Float16)u.w;
            half4_t gh = {g0, g1, g2, g3};
            half4_t gl = {(_Float16)((u.x - (float)g0) * LO_SCALE),
                          (_Float16)((u.y - (float)g1) * LO_SCALE),
                          (_Float16)((u.z - (float)g2) * LO_SCALE),
                          (_Float16)((u.w - (float)g3) * LO_SCALE)};
            *(half4_t*)&sb[row[p] * 40 + c4[p]] = gh;
            *(half4_t*)&sb[5120 + row[p] * 40 + c4[p]] = gl;
        }
        __syncthreads();
        if (kt < 31) {
            int kb = (kt + 1) * 32;
#pragma unroll
            for (int p = 0; p < 4; ++p) {
                ra[p] = *(const float4*)&Ab[(size_t)row[p] * 32768 + kb + c4[p]];
                rw[p] = *(const float4*)&Wb[(size_t)row[p] * 32768 + kb + c4[p]];
            }
        }
        int koff = (lane >> 4) * 8;
        int fr = lane & 15;
        half8 bh[4], bl[4];
#pragma unroll
        for (int nf = 0; nf < 4; ++nf) {
            int r = wn + nf * 16 + fr;
            bh[nf] = *(const half8*)&sb[r * 40 + koff];
            bl[nf] = *(const half8*)&sb[5120 + r * 40 + koff];
        }
#pragma unroll
        for (int mf = 0; mf < 4; ++mf) {
            int r = wm + mf * 16 + fr;
            half8 ah = *(const half8*)&sa[r * 40 + koff];
            half8 al = *(const half8*)&sa[5120 + r * 40 + koff];
#pragma unroll
            for (int nf = 0; nf < 4; ++nf) {
                acc1[mf][nf] = __builtin_amdgcn_mfma_f32_16x16x32_f16(
                    ah, bh[nf], acc1[mf][nf], 0, 0, 0);
                acc2[mf][nf] = __builtin_amdgcn_mfma_f32_16x16x32_f16(
                    ah, bl[nf], acc2[mf][nf], 0, 0, 0);
                acc2[mf][nf] = __builtin_amdgcn_mfma_f32_16x16x32_f16(
                    al, bh[nf], acc2[mf][nf], 0, 0, 0);
            }
        }
        __syncthreads();
    }

    int rq = lane >> 4, cn = lane & 15;
    float* pb = partial + (size_t)ks * 262144;
#pragma unroll
    for (int mf = 0; mf < 4; ++mf)
#pragma unroll
        for (int nf = 0; nf < 4; ++nf) {
            int n = n0 + wn + nf * 16 + cn;
#pragma unroll
            for (int r = 0; r < 4; ++r) {
                int m = m0 + wm + mf * 16 + rq * 4 + r;
                pb[(size_t)m * 1024 + n] = acc1[mf][nf][r] + acc2[mf][nf][r] * LO_INV;
            }
        }
}

__global__ __launch_bounds__(256)
void fc1red_k(const float* __restrict__ partial, const float* __restrict__ b1,
              float* __restrict__ fc1o_t /* [n][m] */) {
    int m = blockIdx.x;
    int n0 = threadIdx.x * 4;
    float4 s = {0.f, 0.f, 0.f, 0.f};
    for (int ks = 0; ks < 32; ++ks) {
        float4 v = *(const float4*)&partial[((size_t)ks * 256 + m) * 1024 + n0];
        s.x += v.x; s.y += v.y; s.z += v.z; s.w += v.w;
    }
    fc1o_t[(size_t)(n0 + 0) * 256 + m] = fmaxf(s.x + b1[n0 + 0], 0.f);
    fc1o_t[(size_t)(n0 + 1) * 256 + m] = fmaxf(s.y + b1[n0 + 1], 0.f);
    fc1o_t[(size_t)(n0 + 2) * 256 + m] = fmaxf(s.z + b1[n0 + 2], 0.f);
    fc1o_t[(size_t)(n0 + 3) * 256 + m] = fmaxf(s.w + b1[n0 + 3], 0.f);
}

__global__ __launch_bounds__(256)
void fc2a_k(const float* __restrict__ a_t, const float* __restrict__ W2,
            float* __restrict__ p2) {
    int n2 = blockIdx.x, ks = blockIdx.y;
    int m = threadIdx.x;
    float acc = 0.f;
    for (int k = ks * 256; k < ks * 256 + 256; ++k)
        acc = fmaf(a_t[(size_t)k * 256 + m], W2[n2 * 1024 + k], acc);
    p2[((size_t)n2 * 4 + ks) * 256 + m] = acc;
}

__global__ __launch_bounds__(512)
void fc2b_k(const float* __restrict__ p2, const float* __restrict__ b2,
            float* __restrict__ out) {
    int i = threadIdx.x;
    int m = i >> 1, n2 = i & 1;
    float s = b2[n2];
#pragma unroll
    for (int ks = 0; ks < 4; ++ks) s += p2[((size_t)n2 * 4 + ks) * 256 + m];
    out[m * 2 + n2] = s;
}

// ---------------------------------------------------------------------------
extern "C" void kernel_launch(void* const* d_in, const int* in_sizes, int n_in,
                              void* d_out, int out_size, void* d_ws, size_t ws_size,
                              hipStream_t stream) {
    const float* image   = (const float*)d_in[0];
    const int*   question= (const int*)d_in[1];
    const float* stem_w0 = (const float*)d_in[2];
    const float* stem_b0 = (const float*)d_in[3];
    const float* stem_w  = (const float*)d_in[4];
    const float* stem_b  = (const float*)d_in[5];
    const float* exp_w1  = (const float*)d_in[6];
    const float* exp_b1  = (const float*)d_in[7];
    const float* exp_w2  = (const float*)d_in[8];
    const float* exp_b2  = (const float*)d_in[9];
    const float* proj_w  = (const float*)d_in[10];
    const float* proj_b  = (const float*)d_in[11];
    const float* fc1_w   = (const float*)d_in[12];
    const float* fc1_b   = (const float*)d_in[13];
    const float* fc2_w   = (const float*)d_in[14];
    const float* fc2_b   = (const float*)d_in[15];
    (void)in_sizes; (void)n_in; (void)out_size; (void)ws_size;

    float* ws = (float*)d_ws;
    const size_t A = 16777216, P2N = 4194304;
    float* p1    = ws;
    float* h2    = ws + A;
    float* p2    = ws + 2 * A;
    float* wtr   = ws + 2 * A + P2N;
    float* w0t   = wtr;                      // 1728 fp32
    _Float16* pwF = (_Float16*)(wtr + 1728); // 65536 f16
    float* pfc2  = wtr + 1728 + 32768;       // 2048 fp32
    _Float16* f16b = (_Float16*)(wtr + 36544);
    _Float16* stemtF = f16b;                 // 3 layers * 73728 f16
    _Float16* e1tF   = f16b + 3 * 73728;     // 16 layers
    _Float16* e2tF   = e1tF + 16 * 73728;    // 16 layers
    float* hA    = ws;
    float* hB    = ws + P2N;
    float* hC    = ws + 2 * P2N;
    float* pool3 = h2;
    float* fc1o  = h2 + 8388608;
    float* fc1p  = ws;

    // weight transforms
    transw_k<<<(1728 + 255) / 256, 256, 0, stream>>>(stem_w0, w0t, 64, 3, 9, 1728);
    pwxform_k<<<128, 256, 0, stream>>>(proj_w, pwF);
    wxform_k<<<(3 * 36864 + 255) / 256, 256, 0, stream>>>(stem_w, stemtF, 3);
    wxform_k<<<(16 * 36864 + 255) / 256, 256, 0, stream>>>(exp_w1, e1tF, 16);
    wxform_k<<<(16 * 36864 + 255) / 256, 256, 0, stream>>>(exp_w2, e2tF, 16);

    // stem
    conv1_k<<<dim3(256, 4, 4), 256, 0, stream>>>(image, w0t, stem_b0, p1);
    convm_k<32, false, false><<<dim3(256, 8), 256, 0, stream>>>(
        p1, h2, stemtF, stem_b, nullptr, nullptr, 0);
    convm_k<32, true, false><<<dim3(256, 8), 256, 0, stream>>>(
        h2, p2, stemtF + 73728, stem_b + 64, nullptr, nullptr, 0);
    convm_k<16, false, false><<<dim3(256, 2), 256, 0, stream>>>(
        p2, hA, stemtF + 2 * 73728, stem_b + 128, nullptr, nullptr, 0);

    // expert residual rounds (cols 4,5,7)
    const int cols[3] = {4, 5, 7};
    float* hin = hA;
    float* hmid = hB;
    float* hout = hC;
    for (int r = 0; r < 3; ++r) {
        convm_k<16, false, false><<<dim3(256, 2), 256, 0, stream>>>(
            hin, hmid, e1tF, exp_b1, nullptr, question, cols[r]);
        convm_k<16, false, true><<<dim3(256, 2), 256, 0, stream>>>(
            hmid, hout, e2tF, exp_b2, hin, question, cols[r]);
        float* tp = hin; hin = hout; hout = hmid; hmid = tp;
    }
    // hin == final h (ws+0)

    // head
    projm_k<<<dim3(256, 2), 256, 0, stream>>>(hin, pwF, proj_b, pool3);
    fc1m_k<<<512, 256, 0, stream>>>(pool3, fc1_w, fc1p);
    fc1red_k<<<256, 256, 0, stream>>>(fc1p, fc1_b, fc1o);
    fc2a_k<<<dim3(2, 4), 256, 0, stream>>>(fc1o, fc2_w, pfc2);
    fc2b_k<<<1, 512, 0, stream>>>(pfc2, fc2_b, (float*)d_out);
}